// Round 2
// baseline (264.848 us; speedup 1.0000x reference)
//
#include <hip/hip_runtime.h>
#include <cfloat>

#define TOKENS 32768
#define DIM    320
#define K      16
#define NCODE  8192

#define NSPLIT 4
#define SPAN   (NCODE / NSPLIT)   // 2048 codes per split
#define NTILE  (SPAN / 32)        // 64 tiles of 32 codes
#define EPS    2.5e-4f
#define FBWAVES 1024              // fallback kernel total waves

typedef __attribute__((ext_vector_type(8)))  short short8;
typedef __attribute__((ext_vector_type(16))) float f32x16;
typedef unsigned short ushort_t;
typedef unsigned int   uint_t;

// RNE float -> bf16 (no NaN handling needed; inputs finite)
static __device__ __forceinline__ ushort_t f2bf(float f) {
    uint_t u = __float_as_uint(f);
    u += 0x7fffu + ((u >> 16) & 1u);
    return (ushort_t)(u >> 16);
}
static __device__ __forceinline__ float bf2f(ushort_t h) {
    return __uint_as_float(((uint_t)h) << 16);
}
static __device__ __forceinline__ uint_t pack2(ushort_t a, ushort_t b) {
    return (uint_t)a | ((uint_t)b << 16);
}

// ---------------------------------------------------------------------------
// prep: blocks [0,1024): projection+normalize+split (8 lanes per token).
//       blocks [1024,1056): codebook c2 + bf16 hi/lo split.
// ---------------------------------------------------------------------------
__global__ __launch_bounds__(256) void prep_kernel(
    const float* __restrict__ x,     // (32768, 320)
    const float* __restrict__ P,     // (320, 16)
    const float* __restrict__ cb,    // (8192, 16)
    float* __restrict__ tn,          // (32768,16) fp32 (fallback)
    float* __restrict__ x2o,         // (32768)
    float* __restrict__ c2o,         // (8192)
    float* __restrict__ c2h,         // (8192)  c2/2
    ushort_t* __restrict__ tnpack,   // (32768,32) [hi16|lo16]
    ushort_t* __restrict__ cbpack,   // (8192,32)  [hi16|lo16]
    int* __restrict__ cnt)
{
    int tid = threadIdx.x;
    int bid = blockIdx.x;
    if (bid < TOKENS / 32) {
        int tok = bid * 32 + (tid >> 3);
        int sub = tid & 7;
        const float* xr = x + (size_t)tok * DIM;
        float acc[16];
        #pragma unroll
        for (int k = 0; k < 16; ++k) acc[k] = 0.f;
        // d = sub + 8*i, 40 steps; P row loads are L1-hot (20 KB total)
        for (int i = 0; i < 40; ++i) {
            int d = sub + (i << 3);
            float xv = xr[d];
            const float4* pr = (const float4*)(P + d * 16);
            float4 p0 = pr[0], p1 = pr[1], p2 = pr[2], p3 = pr[3];
            acc[0] = fmaf(xv, p0.x, acc[0]);  acc[1] = fmaf(xv, p0.y, acc[1]);
            acc[2] = fmaf(xv, p0.z, acc[2]);  acc[3] = fmaf(xv, p0.w, acc[3]);
            acc[4] = fmaf(xv, p1.x, acc[4]);  acc[5] = fmaf(xv, p1.y, acc[5]);
            acc[6] = fmaf(xv, p1.z, acc[6]);  acc[7] = fmaf(xv, p1.w, acc[7]);
            acc[8] = fmaf(xv, p2.x, acc[8]);  acc[9] = fmaf(xv, p2.y, acc[9]);
            acc[10] = fmaf(xv, p2.z, acc[10]); acc[11] = fmaf(xv, p2.w, acc[11]);
            acc[12] = fmaf(xv, p3.x, acc[12]); acc[13] = fmaf(xv, p3.y, acc[13]);
            acc[14] = fmaf(xv, p3.z, acc[14]); acc[15] = fmaf(xv, p3.w, acc[15]);
        }
        // butterfly over 8 lanes (masks 1,2,4 stay within the group)
        #pragma unroll
        for (int m = 1; m <= 4; m <<= 1) {
            #pragma unroll
            for (int k = 0; k < 16; ++k)
                acc[k] += __shfl_xor(acc[k], m);
        }
        float ss = 0.f;
        #pragma unroll
        for (int k = 0; k < 16; ++k) ss = fmaf(acc[k], acc[k], ss);
        float nrm = fmaxf(sqrtf(ss), 1e-12f);
        float inv = 1.0f / nrm;
        float t[16];
        #pragma unroll
        for (int k = 0; k < 16; ++k) t[k] = acc[k] * inv;
        float xx = 0.f;
        #pragma unroll
        for (int k = 0; k < 16; ++k) xx = fmaf(t[k], t[k], xx);

        // fp32 copy for fallback: lane sub writes elements 2sub, 2sub+1
        float2* tf2 = (float2*)(tn + (size_t)tok * 16);
        tf2[sub] = make_float2(t[2 * sub], t[2 * sub + 1]);

        ushort_t hi[16], lo[16];
        #pragma unroll
        for (int k = 0; k < 16; ++k) {
            hi[k] = f2bf(t[k]);
            lo[k] = f2bf(t[k] - bf2f(hi[k]));
        }
        uint4* dst = (uint4*)(tnpack + (size_t)tok * 32);
        if (sub == 0) dst[0] = make_uint4(pack2(hi[0], hi[1]), pack2(hi[2], hi[3]),
                                          pack2(hi[4], hi[5]), pack2(hi[6], hi[7]));
        if (sub == 1) dst[1] = make_uint4(pack2(hi[8], hi[9]), pack2(hi[10], hi[11]),
                                          pack2(hi[12], hi[13]), pack2(hi[14], hi[15]));
        if (sub == 2) dst[2] = make_uint4(pack2(lo[0], lo[1]), pack2(lo[2], lo[3]),
                                          pack2(lo[4], lo[5]), pack2(lo[6], lo[7]));
        if (sub == 3) dst[3] = make_uint4(pack2(lo[8], lo[9]), pack2(lo[10], lo[11]),
                                          pack2(lo[12], lo[13]), pack2(lo[14], lo[15]));
        if (sub == 4) x2o[tok] = xx;
    } else {
        int j = (bid - TOKENS / 32) * 256 + tid;   // 0..8191
        const float4* cr4 = (const float4*)(cb + (size_t)j * 16);
        float4 c0 = cr4[0], c1 = cr4[1], c2v = cr4[2], c3 = cr4[3];
        float c[16] = {c0.x, c0.y, c0.z, c0.w, c1.x, c1.y, c1.z, c1.w,
                       c2v.x, c2v.y, c2v.z, c2v.w, c3.x, c3.y, c3.z, c3.w};
        float s = 0.f;
        #pragma unroll
        for (int k = 0; k < 16; ++k) s = fmaf(c[k], c[k], s);
        c2o[j] = s;
        c2h[j] = 0.5f * s;
        ushort_t hi[16], lo[16];
        #pragma unroll
        for (int k = 0; k < 16; ++k) {
            hi[k] = f2bf(c[k]);
            lo[k] = f2bf(c[k] - bf2f(hi[k]));
        }
        uint4* dst = (uint4*)(cbpack + (size_t)j * 32);
        dst[0] = make_uint4(pack2(hi[0], hi[1]), pack2(hi[2], hi[3]),
                            pack2(hi[4], hi[5]), pack2(hi[6], hi[7]));
        dst[1] = make_uint4(pack2(hi[8], hi[9]), pack2(hi[10], hi[11]),
                            pack2(hi[12], hi[13]), pack2(hi[14], hi[15]));
        dst[2] = make_uint4(pack2(lo[0], lo[1]), pack2(lo[2], lo[3]),
                            pack2(lo[4], lo[5]), pack2(lo[6], lo[7]));
        dst[3] = make_uint4(pack2(lo[8], lo[9]), pack2(lo[10], lo[11]),
                            pack2(lo[12], lo[13]), pack2(lo[14], lo[15]));
        if (bid == TOKENS / 32 && tid == 0) cnt[0] = 0;
    }
}

// ---------------------------------------------------------------------------
// search: per wave 32 tokens x (split of 2048 codes), 32x32x16 bf16 MFMA x3
// (hi*hi + lo*hi + hi*lo). key = dot - c2/2 (argmax == argmin d2).
// Track per-lane-slot top-2 + argmax, butterfly-merge over 32 col-slots.
// ---------------------------------------------------------------------------
__global__ __launch_bounds__(256) void search_kernel(
    const ushort_t* __restrict__ tnpack,
    const ushort_t* __restrict__ cbpack,
    const float* __restrict__ c2h,
    float* __restrict__ pm1,   // (NSPLIT, TOKENS)
    float* __restrict__ pm2,
    int*   __restrict__ pi1)
{
    int lane = threadIdx.x & 63;
    int wave = threadIdx.x >> 6;
    int half = lane >> 5;
    int l31  = lane & 31;
    int split = blockIdx.y;
    int tbase = blockIdx.x * 128 + wave * 32;

    // A fragments: A[m=l31][k=half*8+j]
    const ushort_t* tp = tnpack + (size_t)(tbase + l31) * 32;
    short8 hiA = *(const short8*)(tp + half * 8);
    short8 loA = *(const short8*)(tp + 16 + half * 8);

    f32x16 zero = {};
    float m1[16], m2[16];
    int   i1[16];
    #pragma unroll
    for (int r = 0; r < 16; ++r) { m1[r] = -FLT_MAX; m2[r] = -FLT_MAX; i1[r] = 0; }

    for (int t = 0; t < NTILE; ++t) {
        int cbase = split * SPAN + t * 32;
        int crow  = cbase + l31;
        const ushort_t* cp = cbpack + (size_t)crow * 32;
        short8 hiB = *(const short8*)(cp + half * 8);
        short8 loB = *(const short8*)(cp + 16 + half * 8);
        float c2hv = c2h[crow];

        f32x16 acc = __builtin_amdgcn_mfma_f32_32x32x16_bf16(hiA, hiB, zero, 0, 0, 0);
        acc = __builtin_amdgcn_mfma_f32_32x32x16_bf16(loA, hiB, acc, 0, 0, 0);
        acc = __builtin_amdgcn_mfma_f32_32x32x16_bf16(hiA, loB, acc, 0, 0, 0);

        int curidx = crow;
        #pragma unroll
        for (int r = 0; r < 16; ++r) {
            float v = acc[r] - c2hv;
            bool g = v > m1[r];
            i1[r] = g ? curidx : i1[r];
            m2[r] = fmaxf(m2[r], fminf(v, m1[r]));
            m1[r] = fmaxf(m1[r], v);
        }
    }

    // merge top-2 across the 32 col-slots (masks stay within 32-lane half)
    #pragma unroll
    for (int mask = 1; mask <= 16; mask <<= 1) {
        #pragma unroll
        for (int r = 0; r < 16; ++r) {
            float a1 = __shfl_xor(m1[r], mask);
            float a2 = __shfl_xor(m2[r], mask);
            int   ai = __shfl_xor(i1[r], mask);
            float nm2 = fmaxf(fminf(m1[r], a1), fmaxf(m2[r], a2));
            i1[r] = (a1 > m1[r]) ? ai : i1[r];
            m1[r] = fmaxf(m1[r], a1);
            m2[r] = nm2;
        }
    }

    // C row = (r&3) + 8*(r>>2) + 4*half; lane l31==r writes that row
    #pragma unroll
    for (int r = 0; r < 16; ++r) {
        if (l31 == r) {
            int mrow = (r & 3) + 8 * (r >> 2) + 4 * half;
            size_t slot = (size_t)split * TOKENS + (tbase + mrow);
            pm1[slot] = m1[r];
            pm2[slot] = m2[r];
            pi1[slot] = i1[r];
        }
    }
}

// ---------------------------------------------------------------------------
// reduce: merge NSPLIT top-2s; certified -> label; else append to flag list.
// ---------------------------------------------------------------------------
__global__ __launch_bounds__(256) void reduce_flag_kernel(
    const float* __restrict__ pm1,
    const float* __restrict__ pm2,
    const int*   __restrict__ pi1,
    int* __restrict__ out,
    int* __restrict__ cnt,
    int* __restrict__ flag)
{
    int tok = blockIdx.x * 256 + threadIdx.x;
    float m1 = pm1[tok], m2 = pm2[tok];
    int   i1 = pi1[tok];
    #pragma unroll
    for (int s = 1; s < NSPLIT; ++s) {
        size_t slot = (size_t)s * TOKENS + tok;
        float a1 = pm1[slot], a2 = pm2[slot];
        int   ai = pi1[slot];
        float nm2 = fmaxf(fminf(m1, a1), fmaxf(m2, a2));
        i1 = (a1 > m1) ? ai : i1;
        m1 = fmaxf(m1, a1);
        m2 = nm2;
    }
    out[tok] = i1;
    if (m1 - m2 <= EPS) {
        int p = atomicAdd(cnt, 1);
        flag[p] = tok;
    }
}

// ---------------------------------------------------------------------------
// fallback: exact fp32 rescan for uncertified tokens, one wave per token.
// Bit-replicates the reference rounding: ascending-k fmaf dot,
// (x2+c2) - 2*dot via fmaf(-2,.), strict-< first-occurrence argmin.
// ---------------------------------------------------------------------------
__global__ __launch_bounds__(256) void fallback_kernel(
    const float* __restrict__ tn,
    const float* __restrict__ x2i,
    const float* __restrict__ cb,
    const float* __restrict__ c2i,
    const int* __restrict__ cnt,
    const int* __restrict__ flag,
    int* __restrict__ out)
{
    int lane = threadIdx.x & 63;
    int wid = blockIdx.x * (blockDim.x >> 6) + (threadIdx.x >> 6);
    int n = cnt[0];
    for (int f = wid; f < n; f += FBWAVES) {
        int tok = flag[f];
        const float4* tr = (const float4*)(tn + (size_t)tok * 16);
        float4 t0 = tr[0], t1 = tr[1], t2 = tr[2], t3 = tr[3];
        float a[16] = {t0.x, t0.y, t0.z, t0.w, t1.x, t1.y, t1.z, t1.w,
                       t2.x, t2.y, t2.z, t2.w, t3.x, t3.y, t3.z, t3.w};
        float xx = x2i[tok];
        float mn = FLT_MAX;
        int   id = 0x7fffffff;
        const float* cbr = cb + (size_t)(lane * 128) * 16;
        for (int jj = 0; jj < 128; ++jj) {
            const float4* c4 = (const float4*)(cbr + jj * 16);
            float4 c0 = c4[0], c1 = c4[1], c2v = c4[2], c3 = c4[3];
            float dot = 0.f;
            dot = fmaf(a[0], c0.x, dot);  dot = fmaf(a[1], c0.y, dot);
            dot = fmaf(a[2], c0.z, dot);  dot = fmaf(a[3], c0.w, dot);
            dot = fmaf(a[4], c1.x, dot);  dot = fmaf(a[5], c1.y, dot);
            dot = fmaf(a[6], c1.z, dot);  dot = fmaf(a[7], c1.w, dot);
            dot = fmaf(a[8], c2v.x, dot); dot = fmaf(a[9], c2v.y, dot);
            dot = fmaf(a[10], c2v.z, dot); dot = fmaf(a[11], c2v.w, dot);
            dot = fmaf(a[12], c3.x, dot); dot = fmaf(a[13], c3.y, dot);
            dot = fmaf(a[14], c3.z, dot); dot = fmaf(a[15], c3.w, dot);
            int j = lane * 128 + jj;
            float e = fmaf(-2.f, dot, xx + c2i[j]);
            if (e < mn) { mn = e; id = j; }
        }
        #pragma unroll
        for (int mask = 1; mask <= 32; mask <<= 1) {
            float pmn = __shfl_xor(mn, mask);
            int   pid = __shfl_xor(id, mask);
            bool take = (pmn < mn) || (pmn == mn && pid < id);
            if (take) { mn = pmn; id = pid; }
        }
        if (lane == 0) out[tok] = id;
    }
}

extern "C" void kernel_launch(void* const* d_in, const int* in_sizes, int n_in,
                              void* d_out, int out_size, void* d_ws, size_t ws_size,
                              hipStream_t stream) {
    const float* x   = (const float*)d_in[0];
    const float* P   = (const float*)d_in[1];
    const float* cbn = (const float*)d_in[2];

    float* ws = (float*)d_ws;
    float* tn    = ws;                                  // 524288
    float* x2    = tn + (size_t)TOKENS * K;             // 32768
    float* c2    = x2 + TOKENS;                         // 8192
    float* c2hp  = c2 + NCODE;                          // 8192
    float* pm1   = c2hp + NCODE;                        // 131072
    float* pm2   = pm1 + (size_t)NSPLIT * TOKENS;       // 131072
    int*   pi1   = (int*)(pm2 + (size_t)NSPLIT * TOKENS); // 131072
    int*   flag  = pi1 + (size_t)NSPLIT * TOKENS;       // 32768
    int*   cnt   = flag + TOKENS;                       // 16 (padded)
    ushort_t* tnpack = (ushort_t*)(cnt + 16);           // 32768*32 ushorts
    ushort_t* cbpack = tnpack + (size_t)TOKENS * 32;    // 8192*32 ushorts
    int* labels = (int*)d_out;

    prep_kernel<<<TOKENS / 32 + NCODE / 256, 256, 0, stream>>>(
        x, P, cbn, tn, x2, c2, c2hp, tnpack, cbpack, cnt);
    dim3 sg(TOKENS / 128, NSPLIT);
    search_kernel<<<sg, 256, 0, stream>>>(tnpack, cbpack, c2hp, pm1, pm2, pi1);
    reduce_flag_kernel<<<TOKENS / 256, 256, 0, stream>>>(pm1, pm2, pi1, labels, cnt, flag);
    fallback_kernel<<<FBWAVES / 4, 256, 0, stream>>>(tn, x2, cbn, c2, cnt, flag, labels);
}

// Round 3
// 229.055 us; speedup vs baseline: 1.1563x; 1.1563x over previous
//
#include <hip/hip_runtime.h>
#include <cfloat>

#define TOKENS 32768
#define DIM    320
#define NCODE  8192
#define NSPLIT 4
#define SPAN   (NCODE / NSPLIT)   // 2048 codes per split
#define NTILE  (SPAN / 32)        // 64 tiles of 32 codes
#define EPS_CERT 3e-4f
#define FBWAVES 2048

typedef __attribute__((ext_vector_type(8)))  short short8;
typedef __attribute__((ext_vector_type(16))) float f32x16;
typedef unsigned short ushort_t;
typedef unsigned int   uint_t;

static __device__ __forceinline__ ushort_t f2bf(float f) {
    uint_t u = __float_as_uint(f);
    u += 0x7fffu + ((u >> 16) & 1u);
    return (ushort_t)(u >> 16);
}
static __device__ __forceinline__ float bf2f(ushort_t h) {
    return __uint_as_float(((uint_t)h) << 16);
}
static __device__ __forceinline__ uint_t pack2(ushort_t a, ushort_t b) {
    return (uint_t)a | ((uint_t)b << 16);
}
static __device__ __forceinline__ uint_t umaxu(uint_t a, uint_t b) { return a > b ? a : b; }
static __device__ __forceinline__ uint_t uminu(uint_t a, uint_t b) { return a < b ? a : b; }

// ---------------------------------------------------------------------------
// prep: blocks [0,256): 1 thread = 1 token. P addressed uniformly (no tid in
// index) -> scalar s_load path; x via batched float4 loads (8 in flight).
// Arithmetic per (tok,k) identical to the validated R1 chain: ascending-d
// fmaf, divide by max(sqrt(ss),1e-12).
// blocks [256,320): codebook c2 + bf16 hi/lo split.
// ---------------------------------------------------------------------------
__global__ __launch_bounds__(128) void prep_kernel(
    const float* __restrict__ x,     // (32768, 320)
    const float* __restrict__ P,     // (320, 16)
    const float* __restrict__ cb,    // (8192, 16)
    float* __restrict__ tn,          // (32768,16) fp32 for fallback
    float* __restrict__ x2o,         // (32768)
    float* __restrict__ c2o,         // (8192)
    ushort_t* __restrict__ tnpack,   // (32768,32) [hi16|lo16]
    ushort_t* __restrict__ cbpack,   // (8192,32)  [hi16|lo16]
    int* __restrict__ cnt)
{
    int bid = blockIdx.x, tid = threadIdx.x;
    if (bid < TOKENS / 128) {
        int tok = bid * 128 + tid;
        const float4* xr = (const float4*)(x + (size_t)tok * DIM);
        float acc[16];
        #pragma unroll
        for (int k = 0; k < 16; ++k) acc[k] = 0.f;
        for (int c = 0; c < 10; ++c) {
            float4 xv[8];
            #pragma unroll
            for (int u = 0; u < 8; ++u) xv[u] = xr[c * 8 + u];
            #pragma unroll
            for (int u = 0; u < 8; ++u) {
                float xs[4] = {xv[u].x, xv[u].y, xv[u].z, xv[u].w};
                #pragma unroll
                for (int e = 0; e < 4; ++e) {
                    int d = c * 32 + u * 4 + e;       // uniform across wave
                    const float* pr = P + d * 16;
                    #pragma unroll
                    for (int k = 0; k < 16; ++k)
                        acc[k] = fmaf(xs[e], pr[k], acc[k]);
                }
            }
        }
        float ss = 0.f;
        #pragma unroll
        for (int k = 0; k < 16; ++k) ss = fmaf(acc[k], acc[k], ss);
        float nrm = fmaxf(sqrtf(ss), 1e-12f);
        float t[16];
        #pragma unroll
        for (int k = 0; k < 16; ++k) t[k] = acc[k] / nrm;
        float xx = 0.f;
        #pragma unroll
        for (int k = 0; k < 16; ++k) xx = fmaf(t[k], t[k], xx);

        float4* tf = (float4*)(tn + (size_t)tok * 16);
        tf[0] = make_float4(t[0], t[1], t[2], t[3]);
        tf[1] = make_float4(t[4], t[5], t[6], t[7]);
        tf[2] = make_float4(t[8], t[9], t[10], t[11]);
        tf[3] = make_float4(t[12], t[13], t[14], t[15]);
        x2o[tok] = xx;

        ushort_t hi[16], lo[16];
        #pragma unroll
        for (int k = 0; k < 16; ++k) {
            hi[k] = f2bf(t[k]);
            lo[k] = f2bf(t[k] - bf2f(hi[k]));
        }
        uint4* dst = (uint4*)(tnpack + (size_t)tok * 32);
        dst[0] = make_uint4(pack2(hi[0], hi[1]), pack2(hi[2], hi[3]),
                            pack2(hi[4], hi[5]), pack2(hi[6], hi[7]));
        dst[1] = make_uint4(pack2(hi[8], hi[9]), pack2(hi[10], hi[11]),
                            pack2(hi[12], hi[13]), pack2(hi[14], hi[15]));
        dst[2] = make_uint4(pack2(lo[0], lo[1]), pack2(lo[2], lo[3]),
                            pack2(lo[4], lo[5]), pack2(lo[6], lo[7]));
        dst[3] = make_uint4(pack2(lo[8], lo[9]), pack2(lo[10], lo[11]),
                            pack2(lo[12], lo[13]), pack2(lo[14], lo[15]));
    } else {
        int j = (bid - TOKENS / 128) * 128 + tid;   // 0..8191
        const float4* cr4 = (const float4*)(cb + (size_t)j * 16);
        float4 c0 = cr4[0], c1 = cr4[1], c2v = cr4[2], c3 = cr4[3];
        float c[16] = {c0.x, c0.y, c0.z, c0.w, c1.x, c1.y, c1.z, c1.w,
                       c2v.x, c2v.y, c2v.z, c2v.w, c3.x, c3.y, c3.z, c3.w};
        float s = 0.f;
        #pragma unroll
        for (int k = 0; k < 16; ++k) s = fmaf(c[k], c[k], s);
        c2o[j] = s;
        ushort_t hi[16], lo[16];
        #pragma unroll
        for (int k = 0; k < 16; ++k) {
            hi[k] = f2bf(c[k]);
            lo[k] = f2bf(c[k] - bf2f(hi[k]));
        }
        uint4* dst = (uint4*)(cbpack + (size_t)j * 32);
        dst[0] = make_uint4(pack2(hi[0], hi[1]), pack2(hi[2], hi[3]),
                            pack2(hi[4], hi[5]), pack2(hi[6], hi[7]));
        dst[1] = make_uint4(pack2(hi[8], hi[9]), pack2(hi[10], hi[11]),
                            pack2(hi[12], hi[13]), pack2(hi[14], hi[15]));
        dst[2] = make_uint4(pack2(lo[0], lo[1]), pack2(lo[2], lo[3]),
                            pack2(lo[4], lo[5]), pack2(lo[6], lo[7]));
        dst[3] = make_uint4(pack2(lo[8], lo[9]), pack2(lo[10], lo[11]),
                            pack2(lo[12], lo[13]), pack2(lo[14], lo[15]));
        if (j == 0) cnt[0] = 0;
    }
}

// ---------------------------------------------------------------------------
// search: wave = 32 tokens x 2048-code split. 3x mfma_32x32x16_bf16 per
// 32-code tile (hi*hi + lo*hi + hi*lo). Epilogue packs key|idx into one u32:
//   p = (bits(dot + 1.0625) & ~8191) | (8191 - j)
// u32 argmax == key argmax with first-occurrence tie-break; top-2 kept for
// certification. 5 VALU ops/pair, 32 regs of state.
// ---------------------------------------------------------------------------
__global__ __launch_bounds__(256, 4) void search_kernel(
    const ushort_t* __restrict__ tnpack,
    const ushort_t* __restrict__ cbpack,
    uint_t* __restrict__ pp1,   // (NSPLIT, TOKENS)
    uint_t* __restrict__ pp2)
{
    int lane = threadIdx.x & 63;
    int wave = threadIdx.x >> 6;
    int half = lane >> 5;
    int l31  = lane & 31;
    int split = blockIdx.y;
    int tbase = blockIdx.x * 128 + wave * 32;

    const ushort_t* tp = tnpack + (size_t)(tbase + l31) * 32;
    short8 hiA = *(const short8*)(tp + half * 8);
    short8 loA = *(const short8*)(tp + 16 + half * 8);

    f32x16 zero = {};
    uint_t p1[16], p2[16];
    #pragma unroll
    for (int r = 0; r < 16; ++r) { p1[r] = 0u; p2[r] = 0u; }

    for (int t = 0; t < NTILE; ++t) {
        int crow = split * SPAN + t * 32 + l31;
        const ushort_t* cp = cbpack + (size_t)crow * 32;
        short8 hiB = *(const short8*)(cp + half * 8);
        short8 loB = *(const short8*)(cp + 16 + half * 8);

        f32x16 acc = __builtin_amdgcn_mfma_f32_32x32x16_bf16(hiA, hiB, zero, 0, 0, 0);
        acc = __builtin_amdgcn_mfma_f32_32x32x16_bf16(loA, hiB, acc, 0, 0, 0);
        acc = __builtin_amdgcn_mfma_f32_32x32x16_bf16(hiA, loB, acc, 0, 0, 0);

        uint_t inv = 8191u - (uint_t)crow;
        #pragma unroll
        for (int r = 0; r < 16; ++r) {
            uint_t kb = __float_as_uint(acc[r] + 1.0625f);
            uint_t p  = (kb & 0xFFFFE000u) | inv;
            p2[r] = umaxu(p2[r], uminu(p, p1[r]));
            p1[r] = umaxu(p1[r], p);
        }
    }

    // merge top-2 across the 32 col-slots (masks 1..16 stay within the half)
    #pragma unroll
    for (int mask = 1; mask <= 16; mask <<= 1) {
        #pragma unroll
        for (int r = 0; r < 16; ++r) {
            uint_t a1 = (uint_t)__shfl_xor((int)p1[r], mask);
            uint_t a2 = (uint_t)__shfl_xor((int)p2[r], mask);
            uint_t np2 = umaxu(uminu(p1[r], a1), umaxu(p2[r], a2));
            p1[r] = umaxu(p1[r], a1);
            p2[r] = np2;
        }
    }

    // C/D row = (r&3) + 8*(r>>2) + 4*half
    #pragma unroll
    for (int r = 0; r < 16; ++r) {
        if (l31 == r) {
            int mrow = (r & 3) + 8 * (r >> 2) + 4 * half;
            size_t slot = (size_t)split * TOKENS + (tbase + mrow);
            pp1[slot] = p1[r];
            pp2[slot] = p2[r];
        }
    }
}

// ---------------------------------------------------------------------------
// reduce: merge NSPLIT packed top-2s, decode label, certify with rigorous
// float bounds (quantization accounted via the 13-bit mask), flag the rest.
// ---------------------------------------------------------------------------
__global__ __launch_bounds__(256) void reduce_flag_kernel(
    const uint_t* __restrict__ pp1,
    const uint_t* __restrict__ pp2,
    int* __restrict__ out,
    int* __restrict__ cnt,
    int* __restrict__ flag)
{
    int tok = blockIdx.x * 256 + threadIdx.x;
    uint_t p1 = pp1[tok], p2 = pp2[tok];
    #pragma unroll
    for (int s = 1; s < NSPLIT; ++s) {
        uint_t a1 = pp1[(size_t)s * TOKENS + tok];
        uint_t a2 = pp2[(size_t)s * TOKENS + tok];
        uint_t np2 = umaxu(uminu(p1, a1), umaxu(p2, a2));
        p1 = umaxu(p1, a1);
        p2 = np2;
    }
    out[tok] = 8191 - (int)(p1 & 8191u);
    float f1lo = __uint_as_float(p1 & 0xFFFFE000u);
    float f2hi = __uint_as_float((p2 & 0xFFFFE000u) + 0x2000u);
    if (f1lo - f2hi <= EPS_CERT) {
        int pz = atomicAdd(cnt, 1);
        flag[pz] = tok;
    }
}

// ---------------------------------------------------------------------------
// fallback: exact fp32 rescan for uncertified tokens (R1-validated math:
// ascending fmaf dot, fmaf(-2,dot,x2+c2), strict-< first-occurrence).
// j = jj*64+lane -> coalesced cb/c2 loads.
// ---------------------------------------------------------------------------
__global__ __launch_bounds__(256) void fallback_kernel(
    const float* __restrict__ tn,
    const float* __restrict__ x2i,
    const float* __restrict__ cb,
    const float* __restrict__ c2i,
    const int* __restrict__ cnt,
    const int* __restrict__ flag,
    int* __restrict__ out)
{
    int lane = threadIdx.x & 63;
    int wid = blockIdx.x * 4 + (threadIdx.x >> 6);
    int n = cnt[0];
    for (int f = wid; f < n; f += FBWAVES) {
        int tok = flag[f];
        const float4* tr = (const float4*)(tn + (size_t)tok * 16);
        float4 t0 = tr[0], t1 = tr[1], t2 = tr[2], t3 = tr[3];
        float a[16] = {t0.x, t0.y, t0.z, t0.w, t1.x, t1.y, t1.z, t1.w,
                       t2.x, t2.y, t2.z, t2.w, t3.x, t3.y, t3.z, t3.w};
        float xx = x2i[tok];
        float mn = FLT_MAX;
        int   id = 0x7fffffff;
        for (int jj = 0; jj < 128; ++jj) {
            int j = jj * 64 + lane;
            const float4* c4 = (const float4*)(cb + (size_t)j * 16);
            float4 c0 = c4[0], c1 = c4[1], c2v = c4[2], c3 = c4[3];
            float dot = 0.f;
            dot = fmaf(a[0], c0.x, dot);   dot = fmaf(a[1], c0.y, dot);
            dot = fmaf(a[2], c0.z, dot);   dot = fmaf(a[3], c0.w, dot);
            dot = fmaf(a[4], c1.x, dot);   dot = fmaf(a[5], c1.y, dot);
            dot = fmaf(a[6], c1.z, dot);   dot = fmaf(a[7], c1.w, dot);
            dot = fmaf(a[8], c2v.x, dot);  dot = fmaf(a[9], c2v.y, dot);
            dot = fmaf(a[10], c2v.z, dot); dot = fmaf(a[11], c2v.w, dot);
            dot = fmaf(a[12], c3.x, dot);  dot = fmaf(a[13], c3.y, dot);
            dot = fmaf(a[14], c3.z, dot);  dot = fmaf(a[15], c3.w, dot);
            float e = fmaf(-2.f, dot, xx + c2i[j]);
            if (e < mn) { mn = e; id = j; }
        }
        #pragma unroll
        for (int mask = 1; mask <= 32; mask <<= 1) {
            float pmn = __shfl_xor(mn, mask);
            int   pid = __shfl_xor(id, mask);
            bool take = (pmn < mn) || (pmn == mn && pid < id);
            if (take) { mn = pmn; id = pid; }
        }
        if (lane == 0) out[tok] = id;
    }
}

extern "C" void kernel_launch(void* const* d_in, const int* in_sizes, int n_in,
                              void* d_out, int out_size, void* d_ws, size_t ws_size,
                              hipStream_t stream) {
    const float* x   = (const float*)d_in[0];
    const float* P   = (const float*)d_in[1];
    const float* cbn = (const float*)d_in[2];

    float* ws = (float*)d_ws;
    float*  tn   = ws;                                    // 524288 f
    float*  x2   = tn + (size_t)TOKENS * 16;              // 32768 f
    float*  c2   = x2 + TOKENS;                           // 8192 f
    uint_t* pp1  = (uint_t*)(c2 + NCODE);                 // 131072 u32
    uint_t* pp2  = pp1 + (size_t)NSPLIT * TOKENS;         // 131072 u32
    int*    flag = (int*)(pp2 + (size_t)NSPLIT * TOKENS); // 32768 i32
    int*    cnt  = flag + TOKENS;                         // 16
    ushort_t* tnpack = (ushort_t*)(cnt + 16);             // 32768*32 us
    ushort_t* cbpack = tnpack + (size_t)TOKENS * 32;      // 8192*32 us
    int* labels = (int*)d_out;

    prep_kernel<<<TOKENS / 128 + NCODE / 128, 128, 0, stream>>>(
        x, P, cbn, tn, x2, c2, tnpack, cbpack, cnt);
    dim3 sg(TOKENS / 128, NSPLIT);
    search_kernel<<<sg, 256, 0, stream>>>(tnpack, cbpack, pp1, pp2);
    reduce_flag_kernel<<<TOKENS / 256, 256, 0, stream>>>(pp1, pp2, labels, cnt, flag);
    fallback_kernel<<<FBWAVES / 4, 256, 0, stream>>>(tn, x2, cbn, c2, cnt, flag, labels);
}